// Round 6
// baseline (233.491 us; speedup 1.0000x reference)
//
#include <hip/hip_runtime.h>

#define NCLS 19
#define HWSZ (512*1024)
#define NB   8
#define CHUNK 2048            // pixels per block
#define TPX   128             // pixels per staged tile
#define NT    (CHUNK/TPX)     // 16 tiles
#define EPSM  1e-6f
#define EPSPD 1e-6f

#define ROWP 20
#define COLP 32
#define SUMS_ELEMS (NB*2*ROWP*COLP)
#define F4T  (NCLS*TPX/4)     // 608 float4 granules per tensor-tile

typedef short bf16x8 __attribute__((ext_vector_type(8)));
typedef float f32x16 __attribute__((ext_vector_type(16)));
typedef unsigned uint4v __attribute__((ext_vector_type(4)));

// ---------- staging in NAMED registers, 2 sets (depth-2 prefetch) ----------
#define SG_DECL(set) float4 s##set##0, s##set##1, s##set##2, \
                            t##set##0, t##set##1, t##set##2;

// granule g within 128-px row: 0..31.  st=g>>2 (K-step), kg=(g>>1)&1, p=g&1
#define SG_INIT(j) { int f = tid + (j)*256; if ((j) == 2 && f >= F4T) f = F4T - 1; \
    const int row_ = f >> 5, g_ = f & 31;                                          \
    const int blk_ = ((g_ >> 2) << 1) | (g_ & 1);          /* st*2 + p  */         \
    const int slot_ = (((g_ >> 1) & 1) * 20) + row_;       /* kg*20+row */         \
    widx##j = blk_ * 40 + (slot_ ^ (blk_ & 7));                                    \
    goff##j = ((long)(n * NCLS + row_)) * HWSZ + chunk0 + (g_ << 2); }

#define SG_LOAD(set, j, tt) { const long o_ = goff##j + (long)(tt) * TPX; \
    s##set##j = *(const float4*)(S + o_);                                 \
    t##set##j = *(const float4*)(T + o_); }

#define SG_LOADS(set, tt) SG_LOAD(set,0,tt) SG_LOAD(set,1,tt) SG_LOAD(set,2,tt)

#define SG_WRITE(set, j) { Sb4[widx##j] = s##set##j; Tb4[widx##j] = t##set##j; }
#define SG_WRITES(set) SG_WRITE(set,0) SG_WRITE(set,1) SG_WRITE(set,2)

// fp32 -> packed bf16 hi / lo (exact split; hi = truncation, lo = remainder)
#define CVT(pA, pB, HI, LO) {                                                      \
    const unsigned uA = __builtin_bit_cast(unsigned, pA);                          \
    const unsigned uB = __builtin_bit_cast(unsigned, pB);                          \
    HI = __builtin_amdgcn_perm(uB, uA, 0x07060302u);                               \
    const float fa = (pA) - __builtin_bit_cast(float, uA & 0xFFFF0000u);           \
    const float fb = (pB) - __builtin_bit_cast(float, uB & 0xFFFF0000u);           \
    LO = __builtin_amdgcn_perm(__builtin_bit_cast(unsigned, fb),                   \
                               __builtin_bit_cast(unsigned, fa), 0x07060302u); }

#define BBIT(word, sh, ei) { const unsigned lb_ = ((word) >> (sh)) & 255u;         \
    B[ei] = (lb_ == ur) ? (short)0x3F80 : (short)0; }

#define COMPUTE_TILE(t_) {                                                          \
    _Pragma("unroll")                                                               \
    for (int i = 0; i < 4; ++i) {                                                   \
        const uint2 pk = *(const uint2*)(labP + (t_) * TPX + i * 16);               \
        const float4 d0 = xb4[ra[(2*i) & 7]     + (2*i) * 40];                      \
        const float4 d1 = xb4[ra[(2*i+1) & 7]   + (2*i+1) * 40];                    \
        bf16x8 B;                                                                   \
        BBIT(pk.x, 0, 0) BBIT(pk.x, 8, 1) BBIT(pk.x, 16, 2) BBIT(pk.x, 24, 3)      \
        BBIT(pk.y, 0, 4) BBIT(pk.y, 8, 5) BBIT(pk.y, 16, 6) BBIT(pk.y, 24, 7)      \
        unsigned h0, h1, h2, h3, l0_, l1_, l2_, l3_;                                \
        CVT(d0.x, d0.y, h0, l0_)  CVT(d0.z, d0.w, h1, l1_)                          \
        CVT(d1.x, d1.y, h2, l2_)  CVT(d1.z, d1.w, h3, l3_)                          \
        const bf16x8 hi = __builtin_bit_cast(bf16x8, (uint4v){h0, h1, h2, h3});     \
        const bf16x8 lo = __builtin_bit_cast(bf16x8, (uint4v){l0_, l1_, l2_, l3_}); \
        acc = __builtin_amdgcn_mfma_f32_32x32x16_bf16(hi, B, acc, 0, 0, 0);         \
        acc = __builtin_amdgcn_mfma_f32_32x32x16_bf16(lo, B, acc, 0, 0, 0);         \
    } }

#define TILE(set, t_) {                                                             \
    if ((t_) > 0) __syncthreads();                                                  \
    SG_WRITES(set)                                                                  \
    __syncthreads();                                                                \
    if ((t_) + 2 < NT) { SG_LOADS(set, (t_) + 2) }                                  \
    COMPUTE_TILE(t_) }

__global__ __launch_bounds__(256, 5) void icl_sums(
    const float* __restrict__ S, const float* __restrict__ T,
    const int* __restrict__ gt, float* __restrict__ sums)
{
    __shared__ float4 Sb4[16 * 40];            // [blk 0..15][slot 0..39], swizzled
    __shared__ float4 Tb4[16 * 40];
    __shared__ unsigned char labU[CHUNK];      // labels as bytes
    __shared__ float red[2][ROWP][COLP];

    const int tid = threadIdx.x;
    const int n   = blockIdx.y;
    const long chunk0 = (long)blockIdx.x * CHUNK;

    for (int i = tid; i < 2 * ROWP * COLP; i += 256) ((float*)red)[i] = 0.f;

    // prefill count row (slot kg*20+19) in every blk, both buffers; stagers only
    // write rows 0..18, so this persists across all tiles.
    if (tid < 64) {
        const int b = tid >> 2, kg_ = (tid >> 1) & 1, tb = tid & 1;
        const int idx = b * 40 + (((kg_ * 20) + 19) ^ (b & 7));
        (tb ? Tb4 : Sb4)[idx] = make_float4(1.f, 1.f, 1.f, 1.f);
    }

    // labels -> packed u8 in LDS (coalesced)
    {
        const int4* gp = (const int4*)(gt + (long)n * HWSZ + chunk0);
        const int4 a = gp[tid], b = gp[tid + 256];
        const unsigned p0 = (unsigned)a.x | ((unsigned)a.y << 8) |
                            ((unsigned)a.z << 16) | ((unsigned)a.w << 24);
        const unsigned p1 = (unsigned)b.x | ((unsigned)b.y << 8) |
                            ((unsigned)b.z << 16) | ((unsigned)b.w << 24);
        ((unsigned*)labU)[tid]       = p0;
        ((unsigned*)labU)[tid + 256] = p1;
    }

    int widx0, widx1, widx2;
    long goff0, goff1, goff2;
    SG_INIT(0) SG_INIT(1) SG_INIT(2)
    SG_DECL(A) SG_DECL(B)

    const int wave = tid >> 6, lane = tid & 63;
    const int r  = lane & 31;                   // A-row (channel) / B-col (class)
    const int kg = lane >> 5;                   // 8-px half of the 16-px K-step
    const bool isT = wave >= 2;
    const int  ph  = wave & 1;                  // 64-px half of the 128-px tile
    const unsigned ur = (unsigned)r;

    // A-read indices: idx = ph*320 + (2i+p)*40 + (sbase ^ (2i+p))
    const int sbase = kg * 20 + (r < 20 ? r : r - 12);   // r>=20: harmless dup rows
    int ra[8];
#pragma unroll
    for (int k = 0; k < 8; ++k) ra[k] = ph * 320 + (sbase ^ k);

    const float4* xb4 = isT ? Tb4 : Sb4;
    const unsigned char* labP = labU + ph * 64 + kg * 8;

    f32x16 acc = {0,0,0,0,0,0,0,0,0,0,0,0,0,0,0,0};

    SG_LOADS(A, 0)
    SG_LOADS(B, 1)

    TILE(A, 0)  TILE(B, 1)  TILE(A, 2)  TILE(B, 3)
    TILE(A, 4)  TILE(B, 5)  TILE(A, 6)  TILE(B, 7)
    TILE(A, 8)  TILE(B, 9)  TILE(A, 10) TILE(B, 11)
    TILE(A, 12) TILE(B, 13) TILE(A, 14) TILE(B, 15)

    // C/D layout: col = lane&31, row = (e&3) + 8*(e>>2) + 4*(lane>>5)
#pragma unroll
    for (int e = 0; e < 16; ++e) {
        const int row = (e & 3) + 8 * (e >> 2) + 4 * kg;
        if (row < ROWP) atomicAdd(&red[isT ? 1 : 0][row][r], acc[e]);
    }
    __syncthreads();

    float* gs = sums + (long)n * 2 * ROWP * COLP;
    for (int i = tid; i < 2 * ROWP * COLP; i += 256) {
        if ((i & 31) < NCLS) atomicAdd(&gs[i], ((const float*)red)[i]);
    }
}

__global__ __launch_bounds__(256) void icl_final(
    const float* __restrict__ sums, float* __restrict__ out)
{
    __shared__ float v[NB][2][NCLS][NCLS];   // [n][t][k][c]
    __shared__ float red2[256];
    const int tid = threadIdx.x;

    for (int i = tid; i < NB * 2 * NCLS * NCLS; i += 256) {
        const int c = i % NCLS;
        const int k = (i / NCLS) % NCLS;
        const int t = (i / (NCLS * NCLS)) % 2;
        const int n = i / (2 * NCLS * NCLS);
        const float cnt = sums[((n * 2 + 0) * ROWP + NCLS) * COLP + k];
        const float val = sums[((n * 2 + t) * ROWP + c) * COLP + k];
        v[n][t][k][c] = val * (1.f / (cnt + EPSM));
    }
    __syncthreads();

    float acc = 0.f;
    const int NPAIR = NCLS * (NCLS - 1) / 2;   // 171
    for (int i = tid; i < NB * NPAIR; i += 256) {
        const int n = i / NPAIR;
        int rem = i % NPAIR;
        int k1 = 0;
        while (rem >= NCLS - 1 - k1) { rem -= NCLS - 1 - k1; ++k1; }
        const int k2 = k1 + 1 + rem;
        float ss = 0.f, st = 0.f;
#pragma unroll
        for (int c = 0; c < NCLS; ++c) {
            const float ds = v[n][0][k1][c] - v[n][0][k2][c] + EPSPD;
            const float dt = v[n][1][k1][c] - v[n][1][k2][c] + EPSPD;
            ss = fmaf(ds, ds, ss);
            st = fmaf(dt, dt, st);
        }
        const float e = sqrtf(st) - sqrtf(ss);
        acc += 0.5f * e * e;
    }

    red2[tid] = acc;
    __syncthreads();
    for (int s = 128; s > 0; s >>= 1) {
        if (tid < s) red2[tid] += red2[tid + s];
        __syncthreads();
    }
    if (tid == 0) out[0] = 0.5f * red2[0] / (float)NB;
}

extern "C" void kernel_launch(void* const* d_in, const int* in_sizes, int n_in,
                              void* d_out, int out_size, void* d_ws, size_t ws_size,
                              hipStream_t stream) {
    const float* S  = (const float*)d_in[0];
    const float* T  = (const float*)d_in[1];
    const int*   gt = (const int*)d_in[2];

    float* sums = (float*)d_ws;
    hipMemsetAsync(d_ws, 0, SUMS_ELEMS * sizeof(float), stream);

    dim3 grid(HWSZ / CHUNK, NB);   // (256, 8) = 2048 blocks
    icl_sums<<<grid, 256, 0, stream>>>(S, T, gt, sums);
    icl_final<<<1, 256, 0, stream>>>(sums, (float*)d_out);
}

// Round 7
// 196.164 us; speedup vs baseline: 1.1903x; 1.1903x over previous
//
#include <hip/hip_runtime.h>

#define NCLS 19
#define HWSZ (512*1024)
#define NB   8
#define CHUNK 2048            // pixels per block
#define TPX   64              // pixels per staged tile
#define NT    (CHUNK/TPX)     // 32 tiles
#define EPSM  1e-6f
#define EPSPD 1e-6f

#define ROWP 20
#define COLP 32
#define SUMS_ELEMS (NB*2*ROWP*COLP)

#define SLOTS    320          // per tensor per tile: 8 blk * 40 slots
#define BUFSLOTS 640          // S (0..319) + T (320..639)

typedef short bf16x8 __attribute__((ext_vector_type(8)));
typedef float f32x16 __attribute__((ext_vector_type(16)));
typedef unsigned uint4v __attribute__((ext_vector_type(4)));

// fp32 -> packed bf16 hi / lo (exact split; hi = truncation, lo = remainder)
#define CVT(pA, pB, HI, LO) {                                                      \
    const unsigned uA = __builtin_bit_cast(unsigned, pA);                          \
    const unsigned uB = __builtin_bit_cast(unsigned, pB);                          \
    HI = __builtin_amdgcn_perm(uB, uA, 0x07060302u);                               \
    const float fa = (pA) - __builtin_bit_cast(float, uA & 0xFFFF0000u);           \
    const float fb = (pB) - __builtin_bit_cast(float, uB & 0xFFFF0000u);           \
    LO = __builtin_amdgcn_perm(__builtin_bit_cast(unsigned, fb),                   \
                               __builtin_bit_cast(unsigned, fa), 0x07060302u); }

#define BBIT(word, sh, ei) { const unsigned lb_ = ((word) >> (sh)) & 255u;         \
    B[ei] = (lb_ == ur) ? (short)0x3F80 : (short)0; }

// slot inverse: linear slot L -> (tensor, row, pixel-granule); row19 -> dup row0
#define SGI(j) { const int L_ = tid + (j)*256;                                     \
    const int ten_ = (L_ >= SLOTS) ? 1 : 0;                                        \
    const int Ls_ = L_ - ten_*SLOTS;                                               \
    const int blk_ = Ls_ / 40, j40_ = Ls_ - blk_*40;                               \
    const int s_ = j40_ ^ (blk_ & 7);                                              \
    const int kg_ = (s_ >= 20) ? 1 : 0;                                            \
    int row_ = s_ - kg_*20; if (row_ == 19) row_ = 0;                              \
    const int px_ = (blk_ >> 1)*16 + kg_*8 + (blk_ & 1)*4;                         \
    gp##j = (ten_ ? T : S) + ((long)(n*NCLS + row_))*HWSZ + chunk0 + px_; }

#define GLL(gsrc, ldst)                                                            \
    __builtin_amdgcn_global_load_lds(                                              \
        (const __attribute__((address_space(1))) float4*)(gsrc),                   \
        (__attribute__((address_space(3))) float4*)(ldst), 16, 0, 0);

#define ISSUE(tt) { const int d_ = ((tt) & 1) ? BUFSLOTS : 0;                      \
    GLL(gp0 + (tt)*TPX, lsb0 + d_)                                                 \
    GLL(gp1 + (tt)*TPX, lsb1 + d_)                                                 \
    if (tid < 128) { GLL(gp2 + (tt)*TPX, lsb2 + d_) } }

#define WAITK { if (wave < 2) { asm volatile("s_waitcnt vmcnt(3)" ::: "memory"); } \
                else          { asm volatile("s_waitcnt vmcnt(2)" ::: "memory"); } \
                __builtin_amdgcn_sched_barrier(0); }

#define KSTEP(cb_, t_, i_, iA, iB) {                                               \
    const uint2 pk = *(const uint2*)(labU + (t_)*TPX + lo_off + (i_)*16);          \
    const float4 d0 = (cb_)[iA];                                                   \
    const float4 d1 = (cb_)[iB];                                                   \
    bf16x8 B;                                                                      \
    BBIT(pk.x, 0, 0) BBIT(pk.x, 8, 1) BBIT(pk.x, 16, 2) BBIT(pk.x, 24, 3)         \
    BBIT(pk.y, 0, 4) BBIT(pk.y, 8, 5) BBIT(pk.y, 16, 6) BBIT(pk.y, 24, 7)         \
    unsigned h0, h1, h2, h3, l0_, l1_, l2_, l3_;                                   \
    CVT(d0.x, d0.y, h0, l0_)  CVT(d0.z, d0.w, h1, l1_)                             \
    CVT(d1.x, d1.y, h2, l2_)  CVT(d1.z, d1.w, h3, l3_)                             \
    const bf16x8 hi = __builtin_bit_cast(bf16x8, (uint4v){h0, h1, h2, h3});        \
    const bf16x8 lo = __builtin_bit_cast(bf16x8, (uint4v){l0_, l1_, l2_, l3_});    \
    acc = __builtin_amdgcn_mfma_f32_32x32x16_bf16(hi, B, acc, 0, 0, 0);            \
    acc = __builtin_amdgcn_mfma_f32_32x32x16_bf16(lo, B, acc, 0, 0, 0); }

#define COMPUTE(t_) { const float4* cb_ = bufT + (((t_) & 1) ? BUFSLOTS : 0);      \
    KSTEP(cb_, t_, 0, idx00, idx01)                                               \
    KSTEP(cb_, t_, 1, idx10, idx11) }

__global__ __launch_bounds__(256, 5) void icl_sums(
    const float* __restrict__ S, const float* __restrict__ T,
    const int* __restrict__ gt, float* __restrict__ sums)
{
    __shared__ float4 buf[2][BUFSLOTS];        // 20.5 KB, dbuf x [S|T] swizzled slots
    __shared__ unsigned char labU[CHUNK];      // 2 KB
    __shared__ float red[2][ROWP][COLP];       // 5 KB; red[0][19][*] = counts

    const int tid = threadIdx.x;
    const int n   = blockIdx.y;
    const long chunk0 = (long)blockIdx.x * CHUNK;

    for (int i = tid; i < 2 * ROWP * COLP; i += 256) ((float*)red)[i] = 0.f;

    // labels: coalesced -> packed u8 in LDS; keep int4 regs for the histogram
    const int4* gp = (const int4*)(gt + (long)n * HWSZ + chunk0);
    const int4 a = gp[tid], b = gp[tid + 256];
    {
        const unsigned p0 = (unsigned)a.x | ((unsigned)a.y << 8) |
                            ((unsigned)a.z << 16) | ((unsigned)a.w << 24);
        const unsigned p1 = (unsigned)b.x | ((unsigned)b.y << 8) |
                            ((unsigned)b.z << 16) | ((unsigned)b.w << 24);
        ((unsigned*)labU)[tid]       = p0;
        ((unsigned*)labU)[tid + 256] = p1;
    }
    __syncthreads();   // red zeroed + labU visible

    // per-class pixel counts via LDS histogram (exact: integer-valued f32)
    atomicAdd(&red[0][19][a.x], 1.f); atomicAdd(&red[0][19][a.y], 1.f);
    atomicAdd(&red[0][19][a.z], 1.f); atomicAdd(&red[0][19][a.w], 1.f);
    atomicAdd(&red[0][19][b.x], 1.f); atomicAdd(&red[0][19][b.y], 1.f);
    atomicAdd(&red[0][19][b.z], 1.f); atomicAdd(&red[0][19][b.w], 1.f);

    // staging descriptors: per-lane global source = layout-inverse of linear slot
    const float *gp0, *gp1, *gp2;
    SGI(0) SGI(1) SGI(2)

    const int wave = tid >> 6, lane = tid & 63;
    const int r  = lane & 31;                   // A-row (channel) / B-col (class)
    const int kg = lane >> 5;                   // 8-px half of the 16-px K-step
    const bool isT = wave >= 2;                 // waves 0,1 -> S ; 2,3 -> T
    const int  ph  = wave & 1;                  // 32-px half of the 64-px tile
    const unsigned ur = (unsigned)r;
    const int lo_off = ph * 32 + kg * 8;

    // linear LDS segment bases for the 3 staging calls (wave-uniform)
    float4* lsb0 = &buf[0][0] + (wave + 0) * 64;
    float4* lsb1 = &buf[0][0] + (wave + 4) * 64;
    float4* lsb2 = &buf[0][0] + (wave + 8) * 64;   // used by waves 0,1 only

    // A-fragment read slots: blk = st*2+p, slot = kg*20+sr, idx = blk*40+(slot^(blk&7))
    const int sr = (r < 20) ? r : r - 12;       // r>=20: harmless dup rows
    const int sl = kg * 20 + sr;
    const int b00 = (ph*2+0)*2+0, b01 = (ph*2+0)*2+1;
    const int b10 = (ph*2+1)*2+0, b11 = (ph*2+1)*2+1;
    const int idx00 = b00*40 + (sl ^ (b00 & 7));
    const int idx01 = b01*40 + (sl ^ (b01 & 7));
    const int idx10 = b10*40 + (sl ^ (b10 & 7));
    const int idx11 = b11*40 + (sl ^ (b11 & 7));

    const float4* bufT = (const float4*)buf + (isT ? SLOTS : 0);

    f32x16 acc = {0,0,0,0,0,0,0,0,0,0,0,0,0,0,0,0};

    ISSUE(0)
#pragma unroll 2
    for (int t = 0; t < NT - 1; ++t) {
        ISSUE(t + 1)
        WAITK
        __builtin_amdgcn_s_barrier();
        COMPUTE(t)
        __builtin_amdgcn_s_barrier();
    }
    asm volatile("s_waitcnt vmcnt(0)" ::: "memory");
    __builtin_amdgcn_sched_barrier(0);
    __builtin_amdgcn_s_barrier();
    COMPUTE(NT - 1)

    // C/D layout: col = lane&31, row = (e&3) + 8*(e>>2) + 4*kg; row19 = dup row0 -> skip
#pragma unroll
    for (int e = 0; e < 16; ++e) {
        const int row = (e & 3) + 8 * (e >> 2) + 4 * kg;
        if (row < 19) atomicAdd(&red[isT ? 1 : 0][row][r], acc[e]);
    }
    __syncthreads();

    float* gs = sums + (long)n * 2 * ROWP * COLP;
    for (int i = tid; i < 2 * ROWP * COLP; i += 256) {
        if ((i & 31) < NCLS) atomicAdd(&gs[i], ((const float*)red)[i]);
    }
}

__global__ __launch_bounds__(256) void icl_final(
    const float* __restrict__ sums, float* __restrict__ out)
{
    __shared__ float v[NB][2][NCLS][NCLS];   // [n][t][k][c]
    __shared__ float red2[256];
    const int tid = threadIdx.x;

    for (int i = tid; i < NB * 2 * NCLS * NCLS; i += 256) {
        const int c = i % NCLS;
        const int k = (i / NCLS) % NCLS;
        const int t = (i / (NCLS * NCLS)) % 2;
        const int n = i / (2 * NCLS * NCLS);
        const float cnt = sums[((n * 2 + 0) * ROWP + NCLS) * COLP + k];
        const float val = sums[((n * 2 + t) * ROWP + c) * COLP + k];
        v[n][t][k][c] = val * (1.f / (cnt + EPSM));
    }
    __syncthreads();

    float acc = 0.f;
    const int NPAIR = NCLS * (NCLS - 1) / 2;   // 171
    for (int i = tid; i < NB * NPAIR; i += 256) {
        const int n = i / NPAIR;
        int rem = i % NPAIR;
        int k1 = 0;
        while (rem >= NCLS - 1 - k1) { rem -= NCLS - 1 - k1; ++k1; }
        const int k2 = k1 + 1 + rem;
        float ss = 0.f, st = 0.f;
#pragma unroll
        for (int c = 0; c < NCLS; ++c) {
            const float ds = v[n][0][k1][c] - v[n][0][k2][c] + EPSPD;
            const float dt = v[n][1][k1][c] - v[n][1][k2][c] + EPSPD;
            ss = fmaf(ds, ds, ss);
            st = fmaf(dt, dt, st);
        }
        const float e = sqrtf(st) - sqrtf(ss);
        acc += 0.5f * e * e;
    }

    red2[tid] = acc;
    __syncthreads();
    for (int s = 128; s > 0; s >>= 1) {
        if (tid < s) red2[tid] += red2[tid + s];
        __syncthreads();
    }
    if (tid == 0) out[0] = 0.5f * red2[0] / (float)NB;
}

extern "C" void kernel_launch(void* const* d_in, const int* in_sizes, int n_in,
                              void* d_out, int out_size, void* d_ws, size_t ws_size,
                              hipStream_t stream) {
    const float* S  = (const float*)d_in[0];
    const float* T  = (const float*)d_in[1];
    const int*   gt = (const int*)d_in[2];

    float* sums = (float*)d_ws;
    hipMemsetAsync(d_ws, 0, SUMS_ELEMS * sizeof(float), stream);

    dim3 grid(HWSZ / CHUNK, NB);   // (256, 8) = 2048 blocks
    icl_sums<<<grid, 256, 0, stream>>>(S, T, gt, sums);
    icl_final<<<1, 256, 0, stream>>>(sums, (float*)d_out);
}

// Round 8
// 163.167 us; speedup vs baseline: 1.4310x; 1.2022x over previous
//
#include <hip/hip_runtime.h>

#define NCLS 19
#define HWSZ (512*1024)
#define NB   8
#define CHUNK 2048            // pixels per block
#define TPX   64              // pixels per tile
#define NT    (CHUNK/TPX)     // 32 tiles
#define EPSM  1e-6f
#define EPSPD 1e-6f

#define ROWP 20
#define COLP 32
#define SUMS_ELEMS (NB*2*ROWP*COLP)

#define REGION 160            // float4 slots per wave region (152 data + 8 count)
#define DHALF  640            // 4 waves * REGION per dbuf half

typedef short bf16x8 __attribute__((ext_vector_type(8)));
typedef float f32x16 __attribute__((ext_vector_type(16)));
typedef unsigned uint4v __attribute__((ext_vector_type(4)));

// fp32 -> packed bf16 hi / lo (exact split; hi = truncation, lo = remainder)
#define CVT(pA, pB, HI, LO) {                                                      \
    const unsigned uA = __builtin_bit_cast(unsigned, pA);                          \
    const unsigned uB = __builtin_bit_cast(unsigned, pB);                          \
    HI = __builtin_amdgcn_perm(uB, uA, 0x07060302u);                               \
    const float fa = (pA) - __builtin_bit_cast(float, uA & 0xFFFF0000u);           \
    const float fb = (pB) - __builtin_bit_cast(float, uB & 0xFFFF0000u);           \
    LO = __builtin_amdgcn_perm(__builtin_bit_cast(unsigned, fb),                   \
                               __builtin_bit_cast(unsigned, fa), 0x07060302u); }

#define BBIT(word, sh, ei) { const unsigned lb_ = ((word) >> (sh)) & 255u;         \
    B[ei] = (lb_ == ur) ? (short)0x3F80 : (short)0; }

// per-lane staging descriptor j: f = j*64+lane -> (row, granule g) of wave's half
#define SGI(j) { const int f_ = (j)*64 + lane;                                     \
    const int row_ = f_ >> 3, g_ = f_ & 7;                                         \
    const int lb_ = ((g_ >> 2) << 1) | (g_ & 1);                                   \
    const int kg_ = (g_ >> 1) & 1;                                                 \
    lidx##j = lb_*40 + ((kg_*20 + row_) ^ lb_);                                    \
    gp##j = X + ((long)(n*NCLS + (row_ < NCLS ? row_ : 0)))*HWSZ                   \
              + chunk0 + ph*32 + g_*4; }

#define LOADS(set, tt) {                                                           \
    x##set##0 = *(const float4*)(gp0 + (tt)*TPX);                                  \
    x##set##1 = *(const float4*)(gp1 + (tt)*TPX);                                  \
    if (lane < 24) x##set##2 = *(const float4*)(gp2 + (tt)*TPX); }

#define WRITES(set, rg) {                                                          \
    (rg)[lidx0] = x##set##0;                                                       \
    (rg)[lidx1] = x##set##1;                                                       \
    if (lane < 24) (rg)[lidx2] = x##set##2; }

#define KSTEP(cb_, t_, i_, iA, iB) {                                               \
    const uint2 pk = *(const uint2*)(labP + (t_)*TPX + (i_)*16);                   \
    const float4 d0 = (cb_)[iA];                                                   \
    const float4 d1 = (cb_)[iB];                                                   \
    bf16x8 B;                                                                      \
    BBIT(pk.x, 0, 0) BBIT(pk.x, 8, 1) BBIT(pk.x, 16, 2) BBIT(pk.x, 24, 3)         \
    BBIT(pk.y, 0, 4) BBIT(pk.y, 8, 5) BBIT(pk.y, 16, 6) BBIT(pk.y, 24, 7)         \
    unsigned h0, h1, h2, h3, l0_, l1_, l2_, l3_;                                   \
    CVT(d0.x, d0.y, h0, l0_)  CVT(d0.z, d0.w, h1, l1_)                             \
    CVT(d1.x, d1.y, h2, l2_)  CVT(d1.z, d1.w, h3, l3_)                             \
    const bf16x8 hi = __builtin_bit_cast(bf16x8, (uint4v){h0, h1, h2, h3});        \
    const bf16x8 lo = __builtin_bit_cast(bf16x8, (uint4v){l0_, l1_, l2_, l3_});    \
    acc = __builtin_amdgcn_mfma_f32_32x32x16_bf16(hi, B, acc, 0, 0, 0);            \
    acc = __builtin_amdgcn_mfma_f32_32x32x16_bf16(lo, B, acc, 0, 0, 0); }

#define COMPUTE(t_, rg) { KSTEP(rg, t_, 0, idx00, idx01)                           \
                          KSTEP(rg, t_, 1, idx10, idx11) }

#define LDSFENCE { asm volatile("s_waitcnt lgkmcnt(0)" ::: "memory");              \
                   __builtin_amdgcn_sched_barrier(0); }

__global__ __launch_bounds__(256, 4) void icl_sums(
    const float* __restrict__ S, const float* __restrict__ T,
    const int* __restrict__ gt, float* __restrict__ sums)
{
    __shared__ float4 buf4[2*DHALF];           // 20.5 KB: [dbuf][wave][160]
    __shared__ unsigned char labU[CHUNK];      // 2 KB
    __shared__ float red[2][ROWP][COLP];       // 5 KB

    const int tid = threadIdx.x;
    const int n   = blockIdx.y;
    const long chunk0 = (long)blockIdx.x * CHUNK;

    for (int i = tid; i < 2 * ROWP * COLP; i += 256) ((float*)red)[i] = 0.f;

    // labels -> packed u8 in LDS (coalesced, block-shared)
    {
        const int4* gp = (const int4*)(gt + (long)n * HWSZ + chunk0);
        const int4 a = gp[tid], b = gp[tid + 256];
        ((unsigned*)labU)[tid] = (unsigned)a.x | ((unsigned)a.y << 8) |
                                 ((unsigned)a.z << 16) | ((unsigned)a.w << 24);
        ((unsigned*)labU)[tid + 256] = (unsigned)b.x | ((unsigned)b.y << 8) |
                                       ((unsigned)b.z << 16) | ((unsigned)b.w << 24);
    }
    __syncthreads();   // labU + red visible; ONLY block-wide barrier until epilogue

    const int wave = tid >> 6, lane = tid & 63;
    const int r  = lane & 31;                   // A-row (channel) / B-col (class)
    const int kg = lane >> 5;                   // 8-px half of the 16-px K-step
    const bool isT = wave >= 2;                 // waves 0,1 -> S ; 2,3 -> T
    const int  ph  = wave & 1;                  // 32-px half of the 64-px tile
    const unsigned ur = (unsigned)r;

    const float* X = isT ? T : S;

    // staging descriptors (wave-private region, coalesced global source)
    int lidx0, lidx1, lidx2;
    const float *gp0, *gp1, *gp2;
    SGI(0) SGI(1) SGI(2)

    // wave-private dbuf regions
    float4* reg0 = buf4 + wave * REGION;
    float4* reg1 = buf4 + DHALF + wave * REGION;

    // prefill count slots (slot kg*20+19 of each blk) with 1.0 in both regions;
    // stagers only write rows 0..18, so these persist.
    if (lane < 16) {
        const int d_ = lane >> 3, rem = lane & 7, lb = rem >> 1, kg_ = rem & 1;
        buf4[d_*DHALF + wave*REGION + lb*40 + (((kg_*20) + 19) ^ lb)] =
            make_float4(1.f, 1.f, 1.f, 1.f);
    }

    // A-fragment read slots (region-local): blk = i*2+p, slot = kg*20+sr
    const int sr = (r < 20) ? r : r - 12;       // r>=20: harmless dup rows
    const int sl = kg * 20 + sr;
    const int idx00 = 0*40 + (sl ^ 0);
    const int idx01 = 1*40 + (sl ^ 1);
    const int idx10 = 2*40 + (sl ^ 2);
    const int idx11 = 3*40 + (sl ^ 3);

    const unsigned char* labP = labU + ph * 32 + kg * 8;

    f32x16 acc = {0,0,0,0,0,0,0,0,0,0,0,0,0,0,0,0};
    float4 xA0, xA1, xA2, xB0, xB1, xB2;

    LOADS(A, 0)
    LOADS(B, 1)

    for (int t = 0; t < NT; t += 2) {
        WRITES(A, reg0)
        if (t + 2 < NT) { LOADS(A, t + 2) }
        LDSFENCE
        COMPUTE(t, reg0)

        WRITES(B, reg1)
        if (t + 3 < NT) { LOADS(B, t + 3) }
        LDSFENCE
        COMPUTE(t + 1, reg1)
    }

    // C/D layout: col = lane&31, row = (e&3) + 8*(e>>2) + 4*kg (row19 = counts)
#pragma unroll
    for (int e = 0; e < 16; ++e) {
        const int row = (e & 3) + 8 * (e >> 2) + 4 * kg;
        if (row < ROWP) atomicAdd(&red[isT ? 1 : 0][row][r], acc[e]);
    }
    __syncthreads();

    float* gs = sums + (long)n * 2 * ROWP * COLP;
    for (int i = tid; i < 2 * ROWP * COLP; i += 256) {
        if ((i & 31) < NCLS) atomicAdd(&gs[i], ((const float*)red)[i]);
    }
}

__global__ __launch_bounds__(256) void icl_final(
    const float* __restrict__ sums, float* __restrict__ out)
{
    __shared__ float v[NB][2][NCLS][NCLS];   // [n][t][k][c]
    __shared__ float red2[256];
    const int tid = threadIdx.x;

    for (int i = tid; i < NB * 2 * NCLS * NCLS; i += 256) {
        const int c = i % NCLS;
        const int k = (i / NCLS) % NCLS;
        const int t = (i / (NCLS * NCLS)) % 2;
        const int n = i / (2 * NCLS * NCLS);
        const float cnt = sums[((n * 2 + 0) * ROWP + NCLS) * COLP + k];
        const float val = sums[((n * 2 + t) * ROWP + c) * COLP + k];
        v[n][t][k][c] = val * (1.f / (cnt + EPSM));
    }
    __syncthreads();

    float acc = 0.f;
    const int NPAIR = NCLS * (NCLS - 1) / 2;   // 171
    for (int i = tid; i < NB * NPAIR; i += 256) {
        const int n = i / NPAIR;
        int rem = i % NPAIR;
        int k1 = 0;
        while (rem >= NCLS - 1 - k1) { rem -= NCLS - 1 - k1; ++k1; }
        const int k2 = k1 + 1 + rem;
        float ss = 0.f, st = 0.f;
#pragma unroll
        for (int c = 0; c < NCLS; ++c) {
            const float ds = v[n][0][k1][c] - v[n][0][k2][c] + EPSPD;
            const float dt = v[n][1][k1][c] - v[n][1][k2][c] + EPSPD;
            ss = fmaf(ds, ds, ss);
            st = fmaf(dt, dt, st);
        }
        const float e = sqrtf(st) - sqrtf(ss);
        acc += 0.5f * e * e;
    }

    red2[tid] = acc;
    __syncthreads();
    for (int s = 128; s > 0; s >>= 1) {
        if (tid < s) red2[tid] += red2[tid + s];
        __syncthreads();
    }
    if (tid == 0) out[0] = 0.5f * red2[0] / (float)NB;
}

extern "C" void kernel_launch(void* const* d_in, const int* in_sizes, int n_in,
                              void* d_out, int out_size, void* d_ws, size_t ws_size,
                              hipStream_t stream) {
    const float* S  = (const float*)d_in[0];
    const float* T  = (const float*)d_in[1];
    const int*   gt = (const int*)d_in[2];

    float* sums = (float*)d_ws;
    hipMemsetAsync(d_ws, 0, SUMS_ELEMS * sizeof(float), stream);

    dim3 grid(HWSZ / CHUNK, NB);   // (256, 8) = 2048 blocks
    icl_sums<<<grid, 256, 0, stream>>>(S, T, gt, sums);
    icl_final<<<1, 256, 0, stream>>>(sums, (float*)d_out);
}